// Round 16
// baseline (1582.826 us; speedup 1.0000x reference)
//
#include <hip/hip_runtime.h>
#include <hip/hip_bf16.h>
#include <math.h>

// Problem constants
#define B  8
#define NN 511
#define L  512          // n_transit
#define D  1024
#define DFF 4096
#define H  8
#define HD 128
#define NA 5
#define NLAYERS 4
#define ML (B*L)        // 4096 rows

typedef unsigned short u16;
typedef float f32x4  __attribute__((ext_vector_type(4)));
typedef float f32x16 __attribute__((ext_vector_type(16)));
typedef u16   u16x8 __attribute__((ext_vector_type(8)));
typedef u16   u16x4 __attribute__((ext_vector_type(4)));
typedef __bf16 b16x8 __attribute__((ext_vector_type(8)));

__device__ __forceinline__ u16 f2bf(float f) {
    __hip_bfloat16 h = __float2bfloat16(f);
    return __builtin_bit_cast(u16, h);
}
__device__ __forceinline__ float bf2f(u16 u) {
    return __builtin_bit_cast(float, (unsigned)u << 16);
}

__device__ __forceinline__ float gelu_exact(float v) {
    return 0.5f * v * (1.0f + erff(v * 0.70710678118654752440f));
}

__device__ __forceinline__ f32x4 mfma16(u16x8 a, u16x8 b, f32x4 c) {
    return __builtin_amdgcn_mfma_f32_16x16x32_bf16(
        __builtin_bit_cast(b16x8, a), __builtin_bit_cast(b16x8, b), c, 0, 0, 0);
}
__device__ __forceinline__ f32x16 mfma32(u16x8 a, u16x8 b, f32x16 c) {
    return __builtin_amdgcn_mfma_f32_32x32x16_bf16(
        __builtin_bit_cast(b16x8, a), __builtin_bit_cast(b16x8, b), c, 0, 0, 0);
}

__device__ __forceinline__ void gl_lds16(const u16* g, u16* l) {
    __builtin_amdgcn_global_load_lds(
        (const __attribute__((address_space(1))) unsigned int*)g,
        (__attribute__((address_space(3))) unsigned int*)l,
        16, 0, 0);
}

// ---------------------------------------------------------------------------
// Embedding -> bf16 residual stream only
// ---------------------------------------------------------------------------
__global__ void embed_kernel(const float* __restrict__ states,
                             const float* __restrict__ actions,
                             const float* __restrict__ next_states,
                             const float* __restrict__ rewards,
                             const float* __restrict__ pos,
                             const float* __restrict__ ecw,   // (1024,10)
                             const float* __restrict__ ecb,   // (1024)
                             const float* __restrict__ table, // (81,1024)
                             const int*   __restrict__ qs,    // (8,2)
                             u16* __restrict__ xbf) {
    size_t gid = (size_t)blockIdx.x * 256 + threadIdx.x;
    int d   = (int)(gid & (D - 1));
    int row = (int)(gid >> 10);
    int t = row & (L - 1);
    int b = row >> 9;
    float v;
    if (t < NN) {
        const float* w = ecw + (size_t)d * 10;
        int st = b * NN + t;
        float acc = ecb[d];
        acc += states[st*2+0]*w[0] + states[st*2+1]*w[1];
        acc += actions[st*5+0]*w[2] + actions[st*5+1]*w[3] + actions[st*5+2]*w[4]
             + actions[st*5+3]*w[5] + actions[st*5+4]*w[6];
        acc += rewards[st]*w[7];
        acc += next_states[st*2+0]*w[8] + next_states[st*2+1]*w[9];
        v = acc;
    } else {
        int qi = qs[b*2+0] * 9 + qs[b*2+1];
        v = table[(size_t)qi * D + d];
    }
    xbf[(size_t)row * D + d] = f2bf(v + pos[(size_t)t * D + d]);
}

// ---------------------------------------------------------------------------
// Convert ALL weights fp32->bf16 in one kernel (win | wout | wl1 | wl2).
// ---------------------------------------------------------------------------
__global__ void cvt_all_kernel(const float* __restrict__ w_in,
                               const float* __restrict__ w_out,
                               const float* __restrict__ w_l1,
                               const float* __restrict__ w_l2,
                               u16* __restrict__ dst) {
    int i = blockIdx.x * 256 + threadIdx.x;      // 0 .. 3145727
    const float* src;
    int off;
    if (i < 786432)        { src = w_in;  off = i; }
    else if (i < 1048576)  { src = w_out; off = i - 786432; }
    else if (i < 2097152)  { src = w_l1;  off = i - 1048576; }
    else                   { src = w_l2;  off = i - 2097152; }
    float4 v = ((const float4*)src)[off];
    u16x4 o;
    o[0] = f2bf(v.x); o[1] = f2bf(v.y); o[2] = f2bf(v.z); o[3] = f2bf(v.w);
    ((u16x4*)dst)[i] = o;
}

// ---------------------------------------------------------------------------
// 128x128 MFMA GEMM, BK=64, 32x32x16 MFMA. A staged in LDS (16 KB,
// XOR-swizzled); B fragments loaded DIRECT from global (L2-resident
// weights; same bytes the LDS path delivered -> bit-identical).
// C/D frag: col = lane&31, row = (reg&3) + 8*(reg>>2) + 4*(lane>>5)  [m74].
// MODE: 1 = bf16 out + bias (+Vt direct-transpose write for cols>=2048)
//       2 = bf16 out + bias + gelu
// ---------------------------------------------------------------------------
template<int MODE>
__global__ __launch_bounds__(256) void gemm128(
        const u16* __restrict__ A, int lda,
        const u16* __restrict__ Bw, int ldb,
        void* __restrict__ Cout, int ldc,
        const float* __restrict__ bias, int K,
        u16* __restrict__ Vt) {
    __shared__ u16 As[128 * 64];     // 16 KB
    int t = threadIdx.x;
    int w = t >> 6, lane = t & 63;
    int cl = lane & 31, hi = lane >> 5;
    int wr = w >> 1, wc = w & 1;
    int m0 = blockIdx.y * 128, n0 = blockIdx.x * 128;

    // B row pointers for this lane's two N-fragments
    const u16* Brow0 = Bw + (size_t)(n0 + wc * 64 + 0  + cl) * ldb + hi * 8;
    const u16* Brow1 = Bw + (size_t)(n0 + wc * 64 + 32 + cl) * ldb + hi * 8;

    f32x16 acc[2][2] = {};

    for (int k0 = 0; k0 < K; k0 += 64) {
        // stage A tile (4 chunks/thread)
        #pragma unroll
        for (int j = 0; j < 4; ++j) {
            int ch = j * 256 + t;
            int row = ch >> 3;
            int sg = (ch & 7) ^ (row & 7);
            gl_lds16(A + (size_t)(m0 + row) * lda + k0 + sg * 8, As + ch * 8);
        }
        // B fragments direct from global (overlap the staging drain)
        u16x8 bfr[4][2];
        #pragma unroll
        for (int ks = 0; ks < 4; ++ks) {
            bfr[ks][0] = *(const u16x8*)(Brow0 + k0 + ks * 16);
            bfr[ks][1] = *(const u16x8*)(Brow1 + k0 + ks * 16);
        }
        __syncthreads();

        #pragma unroll
        for (int ks = 0; ks < 4; ++ks) {      // K=16 per step
            u16x8 af[2];
            #pragma unroll
            for (int mi = 0; mi < 2; ++mi) {
                int row = wr * 64 + mi * 32 + cl;
                af[mi] = *(const u16x8*)((const char*)As + row * 128 +
                        ((ks * 32 + hi * 16) ^ ((row & 7) << 4)));
            }
            #pragma unroll
            for (int mi = 0; mi < 2; ++mi)
                #pragma unroll
                for (int nj = 0; nj < 2; ++nj)
                    acc[mi][nj] = mfma32(af[mi], bfr[ks][nj], acc[mi][nj]);
        }
        __syncthreads();
    }

    // epilogue: col = lane&31, row = (reg&3) + 8*(reg>>2) + 4*hi
    #pragma unroll
    for (int mi = 0; mi < 2; ++mi) {
        #pragma unroll
        for (int nj = 0; nj < 2; ++nj) {
            int colb = n0 + wc * 64 + nj * 32 + cl;
            float bv = bias[colb];
            #pragma unroll
            for (int rq = 0; rq < 4; ++rq) {
                int rowb = m0 + wr * 64 + mi * 32 + rq * 8 + hi * 4;
                float vv[4];
                #pragma unroll
                for (int rr = 0; rr < 4; ++rr) {
                    float v = acc[mi][nj][rq * 4 + rr] + bv;
                    if (MODE == 2) v = gelu_exact(v);
                    vv[rr] = v;
                    ((u16*)Cout)[(size_t)(rowb + rr) * ldc + colb] = f2bf(v);
                }
                if (MODE == 1 && colb >= 2048) {
                    int b  = rowb >> 9;
                    int l0 = rowb & (L - 1);
                    int hc = colb - 2048;
                    int bh = b * H + (hc >> 7);
                    int d  = hc & (HD - 1);
                    u16x4 pk;
                    pk[0] = f2bf(vv[0]); pk[1] = f2bf(vv[1]);
                    pk[2] = f2bf(vv[2]); pk[3] = f2bf(vv[3]);
                    *(u16x4*)&Vt[((size_t)bh * HD + d) * L + l0] = pk;
                }
            }
        }
    }
}

// ---------------------------------------------------------------------------
// 64x128 MFMA GEMM for N=1024 outputs (out_proj, ff2). A staged (8 KB LDS),
// B direct from global. 32x32x16 MFMA. bf16 out + bias.
// ---------------------------------------------------------------------------
__global__ __launch_bounds__(256) void gemm64(
        const u16* __restrict__ A, int lda,
        const u16* __restrict__ Bw, int ldb,
        u16* __restrict__ Cout, int ldc,
        const float* __restrict__ bias, int K) {
    __shared__ u16 As[64 * 64];      //  8 KB
    int t = threadIdx.x;
    int w = t >> 6, lane = t & 63;
    int cl = lane & 31, hi = lane >> 5;
    int wr = w >> 1, wc = w & 1;     // wave = 32 rows x 64 cols
    int m0 = blockIdx.y * 64, n0 = blockIdx.x * 128;

    const u16* Brow0 = Bw + (size_t)(n0 + wc * 64 + 0  + cl) * ldb + hi * 8;
    const u16* Brow1 = Bw + (size_t)(n0 + wc * 64 + 32 + cl) * ldb + hi * 8;

    f32x16 acc[2] = {};

    for (int k0 = 0; k0 < K; k0 += 64) {
        #pragma unroll
        for (int j = 0; j < 2; ++j) {
            int ch = j * 256 + t;
            int row = ch >> 3;
            int sg = (ch & 7) ^ (row & 7);
            gl_lds16(A + (size_t)(m0 + row) * lda + k0 + sg * 8, As + ch * 8);
        }
        u16x8 bfr[4][2];
        #pragma unroll
        for (int ks = 0; ks < 4; ++ks) {
            bfr[ks][0] = *(const u16x8*)(Brow0 + k0 + ks * 16);
            bfr[ks][1] = *(const u16x8*)(Brow1 + k0 + ks * 16);
        }
        __syncthreads();

        #pragma unroll
        for (int ks = 0; ks < 4; ++ks) {
            int rowA = wr * 32 + cl;
            u16x8 af = *(const u16x8*)((const char*)As + rowA * 128 +
                    ((ks * 32 + hi * 16) ^ ((rowA & 7) << 4)));
            #pragma unroll
            for (int nj = 0; nj < 2; ++nj)
                acc[nj] = mfma32(af, bfr[ks][nj], acc[nj]);
        }
        __syncthreads();
    }

    #pragma unroll
    for (int nj = 0; nj < 2; ++nj) {
        int colb = n0 + wc * 64 + nj * 32 + cl;
        float bv = bias[colb];
        #pragma unroll
        for (int rq = 0; rq < 4; ++rq) {
            int rowb = m0 + wr * 32 + rq * 8 + hi * 4;
            #pragma unroll
            for (int rr = 0; rr < 4; ++rr)
                Cout[(size_t)(rowb + rr) * ldc + colb] = f2bf(acc[nj][rq * 4 + rr] + bv);
        }
    }
}

// ---------------------------------------------------------------------------
// Tail GEMV for the 8 needed rows (one per batch): C[b][n] = act(dot + bias).
// bf16 output (MODE 2 adds gelu).
// ---------------------------------------------------------------------------
template<int MODE>
__global__ void tail_gemv(const u16* __restrict__ A0, long astride,
                          const u16* __restrict__ Wt,
                          const float* __restrict__ bias,
                          u16* __restrict__ C, int N, int K) {
    int b = blockIdx.y;
    int n = blockIdx.x * 256 + threadIdx.x;
    const u16* ar = A0 + (size_t)b * astride;
    const u16* wr = Wt + (size_t)n * K;
    float s = 0.f;
    for (int k = 0; k < K; k += 8) {
        u16x8 av = *(const u16x8*)(ar + k);
        u16x8 wv = *(const u16x8*)(wr + k);
        #pragma unroll
        for (int u = 0; u < 8; ++u) s += bf2f(av[u]) * bf2f(wv[u]);
    }
    s += bias[n];
    if (MODE == 2) s = gelu_exact(s);
    C[(size_t)b * N + n] = f2bf(s);
}

// ---------------------------------------------------------------------------
// Fused attention: per block = one (b,h) x 32 Q-rows. (rounds 3-15 proven)
// ---------------------------------------------------------------------------
__global__ __launch_bounds__(256, 2) void fused_attn(
        const u16* __restrict__ qkv, const u16* __restrict__ Vt,
        float* __restrict__ attnL, u16* __restrict__ ctx) {
    __shared__ u16 Plds[32 * 512];          // 32 KB, XOR-swizzled
    __shared__ float red[4][32];
    int t = threadIdx.x;
    int w = t >> 6, lane = t & 63;
    int c = lane & 15, g = lane >> 4;
    int bh = blockIdx.y, b = bh >> 3, h = bh & 7;
    int q0 = blockIdx.x * 32;

    const u16* Qb = qkv + ((size_t)(b * L + q0)) * (3*D) + h * HD;
    u16x8 qf[2][4];
    #pragma unroll
    for (int i = 0; i < 2; ++i)
        #pragma unroll
        for (int ks = 0; ks < 4; ++ks)
            qf[i][ks] = *(const u16x8*)(Qb + (size_t)(i*16 + c) * (3*D) + ks*32 + g*8);

    const u16* Kb = qkv + ((size_t)(b * L + w * 128)) * (3*D) + D + h * HD;
    f32x4 s[2][8];
    #pragma unroll
    for (int i = 0; i < 2; ++i)
        #pragma unroll
        for (int j = 0; j < 8; ++j)
            s[i][j] = (f32x4){0.f, 0.f, 0.f, 0.f};

    #pragma unroll
    for (int j = 0; j < 8; ++j) {
        u16x8 kf[4];
        #pragma unroll
        for (int ks = 0; ks < 4; ++ks)
            kf[ks] = *(const u16x8*)(Kb + (size_t)(j*16 + c) * (3*D) + ks*32 + g*8);
        #pragma unroll
        for (int i = 0; i < 2; ++i)
            #pragma unroll
            for (int ks = 0; ks < 4; ++ks)
                s[i][j] = mfma16(qf[i][ks], kf[ks], s[i][j]);
    }

    float mx[2][4];
    #pragma unroll
    for (int i = 0; i < 2; ++i)
        #pragma unroll
        for (int r = 0; r < 4; ++r) {
            float m = s[i][0][r];
            #pragma unroll
            for (int j = 1; j < 8; ++j) m = fmaxf(m, s[i][j][r]);
            #pragma unroll
            for (int msk = 1; msk < 16; msk <<= 1)
                m = fmaxf(m, __shfl_xor(m, msk));
            mx[i][r] = m;
        }
    if (c == 0) {
        #pragma unroll
        for (int i = 0; i < 2; ++i)
            #pragma unroll
            for (int r = 0; r < 4; ++r)
                red[w][i*16 + g*4 + r] = mx[i][r];
    }
    __syncthreads();
    float M[2][4];
    #pragma unroll
    for (int i = 0; i < 2; ++i)
        #pragma unroll
        for (int r = 0; r < 4; ++r) {
            int row = i*16 + g*4 + r;
            M[i][r] = fmaxf(fmaxf(red[0][row], red[1][row]),
                            fmaxf(red[2][row], red[3][row]));
        }
    __syncthreads();

    const float KC = 0.08838834764831844f * 1.4426950408889634f;
    float sm[2][4];
    #pragma unroll
    for (int i = 0; i < 2; ++i)
        #pragma unroll
        for (int r = 0; r < 4; ++r) {
            float acc = 0.f;
            #pragma unroll
            for (int j = 0; j < 8; ++j) {
                float e = exp2f((s[i][j][r] - M[i][r]) * KC);
                s[i][j][r] = e;
                acc += e;
            }
            #pragma unroll
            for (int msk = 1; msk < 16; msk <<= 1)
                acc += __shfl_xor(acc, msk);
            sm[i][r] = acc;
        }
    if (c == 0) {
        #pragma unroll
        for (int i = 0; i < 2; ++i)
            #pragma unroll
            for (int r = 0; r < 4; ++r)
                red[w][i*16 + g*4 + r] = sm[i][r];
    }
    __syncthreads();
    float inv[2][4];
    #pragma unroll
    for (int i = 0; i < 2; ++i)
        #pragma unroll
        for (int r = 0; r < 4; ++r) {
            int row = i*16 + g*4 + r;
            inv[i][r] = 1.0f / (red[0][row] + red[1][row] + red[2][row] + red[3][row]);
        }

    char* Pb = (char*)Plds;
    #pragma unroll
    for (int i = 0; i < 2; ++i)
        #pragma unroll
        for (int r = 0; r < 4; ++r) {
            int row = i*16 + g*4 + r;
            int sw = (row & 7) << 4;
            #pragma unroll
            for (int j = 0; j < 8; ++j) {
                int col = w*128 + j*16 + c;
                int a = (row << 10) + (col << 1);
                *(u16*)(Pb + (a ^ sw)) = f2bf(s[i][j][r] * inv[i][r]);
            }
        }
    __syncthreads();

    {
        int row = t >> 3;
        int cb = (t & 7) * 128;
        int sw = (row & 7) << 4;
        float* dst = attnL + (size_t)bh * L * L + (size_t)(q0 + row) * L + (t & 7) * 64;
        #pragma unroll
        for (int u = 0; u < 8; ++u) {
            u16x8 v = *(const u16x8*)(Pb + (((row << 10) + cb + u*16) ^ sw));
            float4 lo, hi;
            lo.x = bf2f(v[0]); lo.y = bf2f(v[1]); lo.z = bf2f(v[2]); lo.w = bf2f(v[3]);
            hi.x = bf2f(v[4]); hi.y = bf2f(v[5]); hi.z = bf2f(v[6]); hi.w = bf2f(v[7]);
            ((float4*)dst)[u*2+0] = lo;
            ((float4*)dst)[u*2+1] = hi;
        }
    }

    const u16* Vb = Vt + ((size_t)bh * HD + w * 32) * L;
    f32x4 o[2][2];
    #pragma unroll
    for (int i = 0; i < 2; ++i)
        #pragma unroll
        for (int j = 0; j < 2; ++j)
            o[i][j] = (f32x4){0.f, 0.f, 0.f, 0.f};

    #pragma unroll
    for (int ks = 0; ks < 16; ++ks) {
        u16x8 aP[2];
        #pragma unroll
        for (int i = 0; i < 2; ++i) {
            int row = i*16 + c;
            int a = (row << 10) + ks*64 + g*16;
            aP[i] = *(const u16x8*)(Pb + (a ^ ((row & 7) << 4)));
        }
        u16x8 vf[2];
        #pragma unroll
        for (int j = 0; j < 2; ++j)
            vf[j] = *(const u16x8*)(Vb + (size_t)(j*16 + c) * L + ks*32 + g*8);
        #pragma unroll
        for (int i = 0; i < 2; ++i)
            #pragma unroll
            for (int j = 0; j < 2; ++j)
                o[i][j] = mfma16(aP[i], vf[j], o[i][j]);
    }

    #pragma unroll
    for (int i = 0; i < 2; ++i)
        #pragma unroll
        for (int j = 0; j < 2; ++j)
            #pragma unroll
            for (int r = 0; r < 4; ++r) {
                int row = q0 + i*16 + g*4 + r;
                int col = h*HD + w*32 + j*16 + c;
                ctx[(size_t)(b * L + row) * D + col] = f2bf(o[i][j][r]);
            }
}

// ---------------------------------------------------------------------------
// Fused residual add + LayerNorm, all-bf16 streams (fp32 internal math).
// TAILX=1: xin row mapped to (row*L + 511). WF32=1: also write fp32 xout.
// ---------------------------------------------------------------------------
template<int TAILX, int WF32>
__global__ void ln_add_kernel(const u16* __restrict__ xin,
                              const u16* __restrict__ yin,
                              u16* __restrict__ xbf,
                              float* __restrict__ xf32,
                              const float* __restrict__ g,
                              const float* __restrict__ bta) {
    int row = blockIdx.x;
    int t = threadIdx.x;
    int w = t >> 6, lane = t & 63;
    size_t xrow = TAILX ? ((size_t)(row * L + (L - 1)) * D) : ((size_t)row * D);
    const u16* xr = xin + xrow;
    const u16* yr = yin + (size_t)row * D;
    u16x4 xv = *(const u16x4*)&xr[t*4];
    u16x4 yv = *(const u16x4*)&yr[t*4];
    float s0 = bf2f(xv[0]) + bf2f(yv[0]), s1 = bf2f(xv[1]) + bf2f(yv[1]);
    float s2 = bf2f(xv[2]) + bf2f(yv[2]), s3 = bf2f(xv[3]) + bf2f(yv[3]);
    __shared__ float wred[8];
    float ps = s0 + s1 + s2 + s3;
    #pragma unroll
    for (int msk = 1; msk < 64; msk <<= 1) ps += __shfl_xor(ps, msk);
    if (lane == 0) wred[w] = ps;
    __syncthreads();
    float mean = (wred[0] + wred[1] + wred[2] + wred[3]) * (1.0f / (float)D);
    float d0 = s0 - mean, d1 = s1 - mean, d2 = s2 - mean, d3 = s3 - mean;
    float pv = d0*d0 + d1*d1 + d2*d2 + d3*d3;
    #pragma unroll
    for (int msk = 1; msk < 64; msk <<= 1) pv += __shfl_xor(pv, msk);
    if (lane == 0) wred[4 + w] = pv;
    __syncthreads();
    float rstd = rsqrtf((wred[4] + wred[5] + wred[6] + wred[7]) * (1.0f / (float)D) + 1e-5f);
    float4 gv = *(const float4*)&g[t*4];
    float4 bv = *(const float4*)&bta[t*4];
    float o0 = d0 * rstd * gv.x + bv.x;
    float o1 = d1 * rstd * gv.y + bv.y;
    float o2 = d2 * rstd * gv.z + bv.z;
    float o3 = d3 * rstd * gv.w + bv.w;
    u16x4 ob;
    ob[0] = f2bf(o0); ob[1] = f2bf(o1); ob[2] = f2bf(o2); ob[3] = f2bf(o3);
    *(u16x4*)&xbf[(size_t)row * D + t*4] = ob;
    if (WF32) {
        float4 of = {o0, o1, o2, o3};
        *(float4*)&(xf32 + (size_t)row * D)[t*4] = of;
    }
}

// ---------------------------------------------------------------------------
// Head: logits + loss + acc, single block. x8 is the compact (8,D) final rows.
// ---------------------------------------------------------------------------
__global__ void head_kernel(const float* __restrict__ x8,
                            const float* __restrict__ pw,
                            const float* __restrict__ pb,
                            const int* __restrict__ tgt,
                            float* __restrict__ out) {
    __shared__ float lg[40];
    int t = threadIdx.x;
    int w = t >> 6, lane = t & 63;
    for (int p = w; p < B * NA; p += 4) {
        int b = p / NA, a = p % NA;
        const float* xr = x8 + (size_t)b * D;
        const float* wr = pw + (size_t)a * D;
        float s = 0.f;
        for (int k = lane; k < D; k += 64) s += xr[k] * wr[k];
        #pragma unroll
        for (int msk = 1; msk < 64; msk <<= 1) s += __shfl_xor(s, msk);
        if (lane == 0) lg[p] = s + pb[a];
    }
    __syncthreads();
    if (t == 0) {
        float loss = 0.f, acc = 0.f;
        for (int b = 0; b < B; ++b) {
            const float* l = lg + b * NA;
            float mx = l[0]; int am = 0;
            for (int a = 1; a < NA; ++a) if (l[a] > mx) { mx = l[a]; am = a; }
            float se = 0.f;
            for (int a = 0; a < NA; ++a) se += expf(l[a] - mx);
            float lse = mx + logf(se);
            float mean_lp = 0.f;
            for (int a = 0; a < NA; ++a) mean_lp += (l[a] - lse);
            mean_lp *= (1.0f / NA);
            int tb = tgt[b];
            float nll = -(l[tb] - lse);
            loss += 0.9f * nll - 0.1f * mean_lp;
            acc += (am == tb) ? 1.f : 0.f;
        }
        out[0] = loss * (1.0f / B);
        out[1] = acc * (1.0f / B);
    }
}

// ---------------------------------------------------------------------------
extern "C" void kernel_launch(void* const* d_in, const int* in_sizes, int n_in,
                              void* d_out, int out_size, void* d_ws, size_t ws_size,
                              hipStream_t stream) {
    const float* states      = (const float*)d_in[0];
    const float* actions     = (const float*)d_in[1];
    const float* next_states = (const float*)d_in[2];
    const float* rewards     = (const float*)d_in[3];
    const float* pos         = (const float*)d_in[4];
    const float* ecw         = (const float*)d_in[5];
    const float* ecb         = (const float*)d_in[6];
    const float* table       = (const float*)d_in[7];
    const float* in_proj_w   = (const float*)d_in[8];
    const float* in_proj_b   = (const float*)d_in[9];
    const float* out_proj_w  = (const float*)d_in[10];
    const float* out_proj_b  = (const float*)d_in[11];
    const float* linear1_w   = (const float*)d_in[12];
    const float* linear1_b   = (const float*)d_in[13];
    const float* linear2_w   = (const float*)d_in[14];
    const float* linear2_b   = (const float*)d_in[15];
    const float* norm1_g     = (const float*)d_in[16];
    const float* norm1_b     = (const float*)d_in[17];
    const float* norm2_g     = (const float*)d_in[18];
    const float* norm2_b     = (const float*)d_in[19];
    const float* pred_w      = (const float*)d_in[20];
    const float* pred_b      = (const float*)d_in[21];
    const int*   query_states   = (const int*)d_in[22];
    const int*   target_actions = (const int*)d_in[23];

    float* out = (float*)d_out;

    // ---- workspace layout (byte offsets) ----
    char* W = (char*)d_ws;
    u16*   x_bf   = (u16*)  (W + 0);                 //  8 MB (bf16 residual)
    u16*   win_bf = (u16*)  (W + 8388608);           //  6 MB  } contiguous
    u16*   wout_bf= (u16*)  (W + 14680064);          //  2 MB  } weight
    u16*   wl1_bf = (u16*)  (W + 16777216);          //  8 MB  } region
    u16*   wl2_bf = (u16*)  (W + 25165824);          //  8 MB  }
    u16*   qkv_bf = (u16*)  (W + 33554432);          // 24 MB
    u16*   Vt     = (u16*)  (W + 58720256);          //  8 MB
    u16*   ff_bf  = (u16*)  (W + 33554432);          // 32 MB (aliases qkv+Vt)
    u16*   ctx_bf = (u16*)  (W + 100663296);         //  8 MB
    u16*   ybf    = (u16*)  (W + 109051904);         //  8 MB (bf16 GEMM y)
    float* fbuf   = (float*)(W + 117440512);         //  8 MB scratch

    // tail scratch lives inside fbuf
    float* x8     = fbuf;                    // 8x1024 f32
    float* xf8    = fbuf + 8192;             // 8x1024 f32
    u16*   y8     = (u16*)(fbuf + 16384);    // 8x1024 bf16
    u16*   x8_bf  = (u16*)(fbuf + 20480);    // 8x1024 bf16
    u16*   ff8_bf = (u16*)(fbuf + 24576);    // 8x4096 bf16
    u16*   y8b    = (u16*)(fbuf + 40960);    // 8x1024 bf16
    u16*   xf8_bf = (u16*)(fbuf + 45056);    // 8x1024 bf16 (sink)

    embed_kernel<<<(ML * D) / 256, 256, 0, stream>>>(
        states, actions, next_states, rewards, pos, ecw, ecb, table,
        query_states, x_bf);

    cvt_all_kernel<<<3145728 / 256, 256, 0, stream>>>(
        in_proj_w, out_proj_w, linear1_w, linear2_w, win_bf);

    const long LL = (long)L * L;
    for (int l = 0; l < NLAYERS; ++l) {
        float* attnL = out + 2 + (size_t)l * B * H * LL;

        // qkv -> bf16 (4096,3072); V also written transposed into Vt
        gemm128<1><<<dim3(3072/128, ML/128), 256, 0, stream>>>(
            x_bf, D, win_bf, D, qkv_bf, 3*D, in_proj_b, D, Vt);

        // fused scores + softmax + d_out P write + PV
        fused_attn<<<dim3(L/32, B*H), 256, 0, stream>>>(qkv_bf, Vt, attnL, ctx_bf);

        if (l < NLAYERS - 1) {
            // out_proj -> bf16   [64x128 tiles: 512 blocks = 2/CU]
            gemm64<<<dim3(D/128, ML/64), 256, 0, stream>>>(
                ctx_bf, D, wout_bf, D, ybf, D, out_proj_b, D);

            // x = LN(x + y)  (in place on bf16 stream)
            ln_add_kernel<0,0><<<ML, 256, 0, stream>>>(
                x_bf, ybf, x_bf, nullptr, norm1_g, norm1_b);

            // ff1 + gelu -> bf16 (4096,4096)
            gemm128<2><<<dim3(DFF/128, ML/128), 256, 0, stream>>>(
                x_bf, D, wl1_bf, D, ff_bf, DFF, linear1_b, D, nullptr);

            // ff2 -> bf16   [64x128 tiles: 512 blocks = 2/CU]
            gemm64<<<dim3(D/128, ML/64), 256, 0, stream>>>(
                ff_bf, DFF, wl2_bf, DFF, ybf, D, linear2_b, DFF);

            ln_add_kernel<0,0><<<ML, 256, 0, stream>>>(
                x_bf, ybf, x_bf, nullptr, norm2_g, norm2_b);
        } else {
            // ---- layer-4 tail: only token 511 of each batch feeds the head ----
            tail_gemv<0><<<dim3(D/256, B), 256, 0, stream>>>(
                ctx_bf + (size_t)(L-1) * D, (long)L * D, wout_bf, out_proj_b,
                y8, D, D);
            ln_add_kernel<1,1><<<B, 256, 0, stream>>>(
                x_bf, y8, x8_bf, x8, norm1_g, norm1_b);
            tail_gemv<2><<<dim3(DFF/256, B), 256, 0, stream>>>(
                x8_bf, (long)D, wl1_bf, linear1_b, ff8_bf, DFF, D);
            tail_gemv<0><<<dim3(D/256, B), 256, 0, stream>>>(
                ff8_bf, (long)DFF, wl2_bf, linear2_b, y8b, D, DFF);
            ln_add_kernel<0,1><<<B, 256, 0, stream>>>(
                x8_bf, y8b, xf8_bf, xf8, norm2_g, norm2_b);
        }
    }

    head_kernel<<<1, 256, 0, stream>>>(xf8, pred_w, pred_b, target_actions, out);
}

// Round 17
// 1108.350 us; speedup vs baseline: 1.4281x; 1.4281x over previous
//
#include <hip/hip_runtime.h>
#include <hip/hip_bf16.h>
#include <math.h>

// Problem constants
#define B  8
#define NN 511
#define L  512          // n_transit
#define D  1024
#define DFF 4096
#define H  8
#define HD 128
#define NA 5
#define NLAYERS 4
#define ML (B*L)        // 4096 rows

typedef unsigned short u16;
typedef float f32x4  __attribute__((ext_vector_type(4)));
typedef float f32x16 __attribute__((ext_vector_type(16)));
typedef u16   u16x8 __attribute__((ext_vector_type(8)));
typedef u16   u16x4 __attribute__((ext_vector_type(4)));
typedef __bf16 b16x8 __attribute__((ext_vector_type(8)));

__device__ __forceinline__ u16 f2bf(float f) {
    __hip_bfloat16 h = __float2bfloat16(f);
    return __builtin_bit_cast(u16, h);
}
__device__ __forceinline__ float bf2f(u16 u) {
    return __builtin_bit_cast(float, (unsigned)u << 16);
}

__device__ __forceinline__ float gelu_exact(float v) {
    return 0.5f * v * (1.0f + erff(v * 0.70710678118654752440f));
}

__device__ __forceinline__ f32x4 mfma16(u16x8 a, u16x8 b, f32x4 c) {
    return __builtin_amdgcn_mfma_f32_16x16x32_bf16(
        __builtin_bit_cast(b16x8, a), __builtin_bit_cast(b16x8, b), c, 0, 0, 0);
}
__device__ __forceinline__ f32x16 mfma32(u16x8 a, u16x8 b, f32x16 c) {
    return __builtin_amdgcn_mfma_f32_32x32x16_bf16(
        __builtin_bit_cast(b16x8, a), __builtin_bit_cast(b16x8, b), c, 0, 0, 0);
}

__device__ __forceinline__ void gl_lds16(const u16* g, u16* l) {
    __builtin_amdgcn_global_load_lds(
        (const __attribute__((address_space(1))) unsigned int*)g,
        (__attribute__((address_space(3))) unsigned int*)l,
        16, 0, 0);
}

// ---------------------------------------------------------------------------
// Embedding -> bf16 residual stream only
// ---------------------------------------------------------------------------
__global__ void embed_kernel(const float* __restrict__ states,
                             const float* __restrict__ actions,
                             const float* __restrict__ next_states,
                             const float* __restrict__ rewards,
                             const float* __restrict__ pos,
                             const float* __restrict__ ecw,   // (1024,10)
                             const float* __restrict__ ecb,   // (1024)
                             const float* __restrict__ table, // (81,1024)
                             const int*   __restrict__ qs,    // (8,2)
                             u16* __restrict__ xbf) {
    size_t gid = (size_t)blockIdx.x * 256 + threadIdx.x;
    int d   = (int)(gid & (D - 1));
    int row = (int)(gid >> 10);
    int t = row & (L - 1);
    int b = row >> 9;
    float v;
    if (t < NN) {
        const float* w = ecw + (size_t)d * 10;
        int st = b * NN + t;
        float acc = ecb[d];
        acc += states[st*2+0]*w[0] + states[st*2+1]*w[1];
        acc += actions[st*5+0]*w[2] + actions[st*5+1]*w[3] + actions[st*5+2]*w[4]
             + actions[st*5+3]*w[5] + actions[st*5+4]*w[6];
        acc += rewards[st]*w[7];
        acc += next_states[st*2+0]*w[8] + next_states[st*2+1]*w[9];
        v = acc;
    } else {
        int qi = qs[b*2+0] * 9 + qs[b*2+1];
        v = table[(size_t)qi * D + d];
    }
    xbf[(size_t)row * D + d] = f2bf(v + pos[(size_t)t * D + d]);
}

// ---------------------------------------------------------------------------
// Convert ALL weights fp32->bf16 in one kernel (win | wout | wl1 | wl2).
// ---------------------------------------------------------------------------
__global__ void cvt_all_kernel(const float* __restrict__ w_in,
                               const float* __restrict__ w_out,
                               const float* __restrict__ w_l1,
                               const float* __restrict__ w_l2,
                               u16* __restrict__ dst) {
    int i = blockIdx.x * 256 + threadIdx.x;      // 0 .. 3145727
    const float* src;
    int off;
    if (i < 786432)        { src = w_in;  off = i; }
    else if (i < 1048576)  { src = w_out; off = i - 786432; }
    else if (i < 2097152)  { src = w_l1;  off = i - 1048576; }
    else                   { src = w_l2;  off = i - 2097152; }
    float4 v = ((const float4*)src)[off];
    u16x4 o;
    o[0] = f2bf(v.x); o[1] = f2bf(v.y); o[2] = f2bf(v.z); o[3] = f2bf(v.w);
    ((u16x4*)dst)[i] = o;
}

// ---------------------------------------------------------------------------
// 128x128 MFMA GEMM, BK=64, single-buffered 32 KB LDS, 32x32x16 MFMA.
// A/B frag: row|col = lane&31, k = (lane>>5)*8 + j  (family pattern).
// C/D frag: col = lane&31, row = (reg&3) + 8*(reg>>2) + 4*(lane>>5)  [m74].
// Staging + XOR swizzle identical to the proven round-8/14 kernel.
// MODE: 1 = bf16 out + bias (+Vt direct-transpose write for cols>=2048)
//       2 = bf16 out + bias + gelu
// ---------------------------------------------------------------------------
template<int MODE>
__global__ __launch_bounds__(256) void gemm128(
        const u16* __restrict__ A, int lda,
        const u16* __restrict__ Bw, int ldb,
        void* __restrict__ Cout, int ldc,
        const float* __restrict__ bias, int K,
        u16* __restrict__ Vt) {
    __shared__ u16 As[128 * 64];
    __shared__ u16 Bs[128 * 64];
    int t = threadIdx.x;
    int w = t >> 6, lane = t & 63;
    int cl = lane & 31, hi = lane >> 5;
    int wr = w >> 1, wc = w & 1;
    int m0 = blockIdx.y * 128, n0 = blockIdx.x * 128;

    f32x16 acc[2][2] = {};

    for (int k0 = 0; k0 < K; k0 += 64) {
        #pragma unroll
        for (int j = 0; j < 4; ++j) {
            int ch = j * 256 + t;
            int row = ch >> 3;
            int sg = (ch & 7) ^ (row & 7);
            gl_lds16(A  + (size_t)(m0 + row) * lda + k0 + sg * 8, As + ch * 8);
            gl_lds16(Bw + (size_t)(n0 + row) * ldb + k0 + sg * 8, Bs + ch * 8);
        }
        __syncthreads();

        #pragma unroll
        for (int ks = 0; ks < 4; ++ks) {      // K=16 per step
            u16x8 af[2], bf[2];
            #pragma unroll
            for (int mi = 0; mi < 2; ++mi) {
                int row = wr * 64 + mi * 32 + cl;
                af[mi] = *(const u16x8*)((const char*)As + row * 128 +
                        ((ks * 32 + hi * 16) ^ ((row & 7) << 4)));
            }
            #pragma unroll
            for (int nj = 0; nj < 2; ++nj) {
                int row = wc * 64 + nj * 32 + cl;
                bf[nj] = *(const u16x8*)((const char*)Bs + row * 128 +
                        ((ks * 32 + hi * 16) ^ ((row & 7) << 4)));
            }
            #pragma unroll
            for (int mi = 0; mi < 2; ++mi)
                #pragma unroll
                for (int nj = 0; nj < 2; ++nj)
                    acc[mi][nj] = mfma32(af[mi], bf[nj], acc[mi][nj]);
        }
        __syncthreads();
    }

    // epilogue: col = lane&31, row = (reg&3) + 8*(reg>>2) + 4*hi
    #pragma unroll
    for (int mi = 0; mi < 2; ++mi) {
        #pragma unroll
        for (int nj = 0; nj < 2; ++nj) {
            int colb = n0 + wc * 64 + nj * 32 + cl;
            float bv = bias[colb];
            #pragma unroll
            for (int rq = 0; rq < 4; ++rq) {
                int rowb = m0 + wr * 64 + mi * 32 + rq * 8 + hi * 4;
                float vv[4];
                #pragma unroll
                for (int rr = 0; rr < 4; ++rr) {
                    float v = acc[mi][nj][rq * 4 + rr] + bv;
                    if (MODE == 2) v = gelu_exact(v);
                    vv[rr] = v;
                    ((u16*)Cout)[(size_t)(rowb + rr) * ldc + colb] = f2bf(v);
                }
                if (MODE == 1 && colb >= 2048) {
                    int b  = rowb >> 9;
                    int l0 = rowb & (L - 1);
                    int hc = colb - 2048;
                    int bh = b * H + (hc >> 7);
                    int d  = hc & (HD - 1);
                    u16x4 pk;
                    pk[0] = f2bf(vv[0]); pk[1] = f2bf(vv[1]);
                    pk[2] = f2bf(vv[2]); pk[3] = f2bf(vv[3]);
                    *(u16x4*)&Vt[((size_t)bh * HD + d) * L + l0] = pk;
                }
            }
        }
    }
}

// ---------------------------------------------------------------------------
// 64x128 MFMA GEMM for N=1024 outputs (out_proj, ff2). 2 blocks/CU. 24 KB
// LDS. 32x32x16 MFMA. bf16 out + bias.
// ---------------------------------------------------------------------------
__global__ __launch_bounds__(256) void gemm64(
        const u16* __restrict__ A, int lda,
        const u16* __restrict__ Bw, int ldb,
        u16* __restrict__ Cout, int ldc,
        const float* __restrict__ bias, int K) {
    __shared__ u16 As[64 * 64];      //  8 KB
    __shared__ u16 Bs[128 * 64];     // 16 KB
    int t = threadIdx.x;
    int w = t >> 6, lane = t & 63;
    int cl = lane & 31, hi = lane >> 5;
    int wr = w >> 1, wc = w & 1;     // wave = 32 rows x 64 cols
    int m0 = blockIdx.y * 64, n0 = blockIdx.x * 128;

    f32x16 acc[2] = {};

    for (int k0 = 0; k0 < K; k0 += 64) {
        #pragma unroll
        for (int j = 0; j < 2; ++j) {
            int ch = j * 256 + t;
            int row = ch >> 3;
            int sg = (ch & 7) ^ (row & 7);
            gl_lds16(A + (size_t)(m0 + row) * lda + k0 + sg * 8, As + ch * 8);
        }
        #pragma unroll
        for (int j = 0; j < 4; ++j) {
            int ch = j * 256 + t;
            int row = ch >> 3;
            int sg = (ch & 7) ^ (row & 7);
            gl_lds16(Bw + (size_t)(n0 + row) * ldb + k0 + sg * 8, Bs + ch * 8);
        }
        __syncthreads();

        #pragma unroll
        for (int ks = 0; ks < 4; ++ks) {
            int rowA = wr * 32 + cl;
            u16x8 af = *(const u16x8*)((const char*)As + rowA * 128 +
                    ((ks * 32 + hi * 16) ^ ((rowA & 7) << 4)));
            u16x8 bf[2];
            #pragma unroll
            for (int nj = 0; nj < 2; ++nj) {
                int row = wc * 64 + nj * 32 + cl;
                bf[nj] = *(const u16x8*)((const char*)Bs + row * 128 +
                        ((ks * 32 + hi * 16) ^ ((row & 7) << 4)));
            }
            #pragma unroll
            for (int nj = 0; nj < 2; ++nj)
                acc[nj] = mfma32(af, bf[nj], acc[nj]);
        }
        __syncthreads();
    }

    #pragma unroll
    for (int nj = 0; nj < 2; ++nj) {
        int colb = n0 + wc * 64 + nj * 32 + cl;
        float bv = bias[colb];
        #pragma unroll
        for (int rq = 0; rq < 4; ++rq) {
            int rowb = m0 + wr * 32 + rq * 8 + hi * 4;
            #pragma unroll
            for (int rr = 0; rr < 4; ++rr)
                Cout[(size_t)(rowb + rr) * ldc + colb] = f2bf(acc[nj][rq * 4 + rr] + bv);
        }
    }
}

// ---------------------------------------------------------------------------
// Tail GEMV for the 8 needed rows (one per batch): C[b][n] = act(dot + bias).
// bf16 output (MODE 2 adds gelu).
// ---------------------------------------------------------------------------
template<int MODE>
__global__ void tail_gemv(const u16* __restrict__ A0, long astride,
                          const u16* __restrict__ Wt,
                          const float* __restrict__ bias,
                          u16* __restrict__ C, int N, int K) {
    int b = blockIdx.y;
    int n = blockIdx.x * 256 + threadIdx.x;
    const u16* ar = A0 + (size_t)b * astride;
    const u16* wr = Wt + (size_t)n * K;
    float s = 0.f;
    for (int k = 0; k < K; k += 8) {
        u16x8 av = *(const u16x8*)(ar + k);
        u16x8 wv = *(const u16x8*)(wr + k);
        #pragma unroll
        for (int u = 0; u < 8; ++u) s += bf2f(av[u]) * bf2f(wv[u]);
    }
    s += bias[n];
    if (MODE == 2) s = gelu_exact(s);
    C[(size_t)b * N + n] = f2bf(s);
}

// ---------------------------------------------------------------------------
// Fused attention: per block = one (b,h) x 32 Q-rows. (rounds 3-15 proven)
// ---------------------------------------------------------------------------
__global__ __launch_bounds__(256, 2) void fused_attn(
        const u16* __restrict__ qkv, const u16* __restrict__ Vt,
        float* __restrict__ attnL, u16* __restrict__ ctx) {
    __shared__ u16 Plds[32 * 512];          // 32 KB, XOR-swizzled
    __shared__ float red[4][32];
    int t = threadIdx.x;
    int w = t >> 6, lane = t & 63;
    int c = lane & 15, g = lane >> 4;
    int bh = blockIdx.y, b = bh >> 3, h = bh & 7;
    int q0 = blockIdx.x * 32;

    const u16* Qb = qkv + ((size_t)(b * L + q0)) * (3*D) + h * HD;
    u16x8 qf[2][4];
    #pragma unroll
    for (int i = 0; i < 2; ++i)
        #pragma unroll
        for (int ks = 0; ks < 4; ++ks)
            qf[i][ks] = *(const u16x8*)(Qb + (size_t)(i*16 + c) * (3*D) + ks*32 + g*8);

    const u16* Kb = qkv + ((size_t)(b * L + w * 128)) * (3*D) + D + h * HD;
    f32x4 s[2][8];
    #pragma unroll
    for (int i = 0; i < 2; ++i)
        #pragma unroll
        for (int j = 0; j < 8; ++j)
            s[i][j] = (f32x4){0.f, 0.f, 0.f, 0.f};

    #pragma unroll
    for (int j = 0; j < 8; ++j) {
        u16x8 kf[4];
        #pragma unroll
        for (int ks = 0; ks < 4; ++ks)
            kf[ks] = *(const u16x8*)(Kb + (size_t)(j*16 + c) * (3*D) + ks*32 + g*8);
        #pragma unroll
        for (int i = 0; i < 2; ++i)
            #pragma unroll
            for (int ks = 0; ks < 4; ++ks)
                s[i][j] = mfma16(qf[i][ks], kf[ks], s[i][j]);
    }

    float mx[2][4];
    #pragma unroll
    for (int i = 0; i < 2; ++i)
        #pragma unroll
        for (int r = 0; r < 4; ++r) {
            float m = s[i][0][r];
            #pragma unroll
            for (int j = 1; j < 8; ++j) m = fmaxf(m, s[i][j][r]);
            #pragma unroll
            for (int msk = 1; msk < 16; msk <<= 1)
                m = fmaxf(m, __shfl_xor(m, msk));
            mx[i][r] = m;
        }
    if (c == 0) {
        #pragma unroll
        for (int i = 0; i < 2; ++i)
            #pragma unroll
            for (int r = 0; r < 4; ++r)
                red[w][i*16 + g*4 + r] = mx[i][r];
    }
    __syncthreads();
    float M[2][4];
    #pragma unroll
    for (int i = 0; i < 2; ++i)
        #pragma unroll
        for (int r = 0; r < 4; ++r) {
            int row = i*16 + g*4 + r;
            M[i][r] = fmaxf(fmaxf(red[0][row], red[1][row]),
                            fmaxf(red[2][row], red[3][row]));
        }
    __syncthreads();

    const float KC = 0.08838834764831844f * 1.4426950408889634f;
    float sm[2][4];
    #pragma unroll
    for (int i = 0; i < 2; ++i)
        #pragma unroll
        for (int r = 0; r < 4; ++r) {
            float acc = 0.f;
            #pragma unroll
            for (int j = 0; j < 8; ++j) {
                float e = exp2f((s[i][j][r] - M[i][r]) * KC);
                s[i][j][r] = e;
                acc += e;
            }
            #pragma unroll
            for (int msk = 1; msk < 16; msk <<= 1)
                acc += __shfl_xor(acc, msk);
            sm[i][r] = acc;
        }
    if (c == 0) {
        #pragma unroll
        for (int i = 0; i < 2; ++i)
            #pragma unroll
            for (int r = 0; r < 4; ++r)
                red[w][i*16 + g*4 + r] = sm[i][r];
    }
    __syncthreads();
    float inv[2][4];
    #pragma unroll
    for (int i = 0; i < 2; ++i)
        #pragma unroll
        for (int r = 0; r < 4; ++r) {
            int row = i*16 + g*4 + r;
            inv[i][r] = 1.0f / (red[0][row] + red[1][row] + red[2][row] + red[3][row]);
        }

    char* Pb = (char*)Plds;
    #pragma unroll
    for (int i = 0; i < 2; ++i)
        #pragma unroll
        for (int r = 0; r < 4; ++r) {
            int row = i*16 + g*4 + r;
            int sw = (row & 7) << 4;
            #pragma unroll
            for (int j = 0; j < 8; ++j) {
                int col = w*128 + j*16 + c;
                int a = (row << 10) + (col << 1);
                *(u16*)(Pb + (a ^ sw)) = f2bf(s[i][j][r] * inv[i][r]);
            }
        }
    __syncthreads();

    {
        int row = t >> 3;
        int cb = (t & 7) * 128;
        int sw = (row & 7) << 4;
        float* dst = attnL + (size_t)bh * L * L + (size_t)(q0 + row) * L + (t & 7) * 64;
        #pragma unroll
        for (int u = 0; u < 8; ++u) {
            u16x8 v = *(const u16x8*)(Pb + (((row << 10) + cb + u*16) ^ sw));
            float4 lo, hi;
            lo.x = bf2f(v[0]); lo.y = bf2f(v[1]); lo.z = bf2f(v[2]); lo.w = bf2f(v[3]);
            hi.x = bf2f(v[4]); hi.y = bf2f(v[5]); hi.z = bf2f(v[6]); hi.w = bf2f(v[7]);
            ((float4*)dst)[u*2+0] = lo;
            ((float4*)dst)[u*2+1] = hi;
        }
    }

    const u16* Vb = Vt + ((size_t)bh * HD + w * 32) * L;
    f32x4 o[2][2];
    #pragma unroll
    for (int i = 0; i < 2; ++i)
        #pragma unroll
        for (int j = 0; j < 2; ++j)
            o[i][j] = (f32x4){0.f, 0.f, 0.f, 0.f};

    #pragma unroll
    for (int ks = 0; ks < 16; ++ks) {
        u16x8 aP[2];
        #pragma unroll
        for (int i = 0; i < 2; ++i) {
            int row = i*16 + c;
            int a = (row << 10) + ks*64 + g*16;
            aP[i] = *(const u16x8*)(Pb + (a ^ ((row & 7) << 4)));
        }
        u16x8 vf[2];
        #pragma unroll
        for (int j = 0; j < 2; ++j)
            vf[j] = *(const u16x8*)(Vb + (size_t)(j*16 + c) * L + ks*32 + g*8);
        #pragma unroll
        for (int i = 0; i < 2; ++i)
            #pragma unroll
            for (int j = 0; j < 2; ++j)
                o[i][j] = mfma16(aP[i], vf[j], o[i][j]);
    }

    #pragma unroll
    for (int i = 0; i < 2; ++i)
        #pragma unroll
        for (int j = 0; j < 2; ++j)
            #pragma unroll
            for (int r = 0; r < 4; ++r) {
                int row = q0 + i*16 + g*4 + r;
                int col = h*HD + w*32 + j*16 + c;
                ctx[(size_t)(b * L + row) * D + col] = f2bf(o[i][j][r]);
            }
}

// ---------------------------------------------------------------------------
// Fused residual add + LayerNorm, all-bf16 streams (fp32 internal math).
// TAILX=1: xin row mapped to (row*L + 511). WF32=1: also write fp32 xout.
// ---------------------------------------------------------------------------
template<int TAILX, int WF32>
__global__ void ln_add_kernel(const u16* __restrict__ xin,
                              const u16* __restrict__ yin,
                              u16* __restrict__ xbf,
                              float* __restrict__ xf32,
                              const float* __restrict__ g,
                              const float* __restrict__ bta) {
    int row = blockIdx.x;
    int t = threadIdx.x;
    int w = t >> 6, lane = t & 63;
    size_t xrow = TAILX ? ((size_t)(row * L + (L - 1)) * D) : ((size_t)row * D);
    const u16* xr = xin + xrow;
    const u16* yr = yin + (size_t)row * D;
    u16x4 xv = *(const u16x4*)&xr[t*4];
    u16x4 yv = *(const u16x4*)&yr[t*4];
    float s0 = bf2f(xv[0]) + bf2f(yv[0]), s1 = bf2f(xv[1]) + bf2f(yv[1]);
    float s2 = bf2f(xv[2]) + bf2f(yv[2]), s3 = bf2f(xv[3]) + bf2f(yv[3]);
    __shared__ float wred[8];
    float ps = s0 + s1 + s2 + s3;
    #pragma unroll
    for (int msk = 1; msk < 64; msk <<= 1) ps += __shfl_xor(ps, msk);
    if (lane == 0) wred[w] = ps;
    __syncthreads();
    float mean = (wred[0] + wred[1] + wred[2] + wred[3]) * (1.0f / (float)D);
    float d0 = s0 - mean, d1 = s1 - mean, d2 = s2 - mean, d3 = s3 - mean;
    float pv = d0*d0 + d1*d1 + d2*d2 + d3*d3;
    #pragma unroll
    for (int msk = 1; msk < 64; msk <<= 1) pv += __shfl_xor(pv, msk);
    if (lane == 0) wred[4 + w] = pv;
    __syncthreads();
    float rstd = rsqrtf((wred[4] + wred[5] + wred[6] + wred[7]) * (1.0f / (float)D) + 1e-5f);
    float4 gv = *(const float4*)&g[t*4];
    float4 bv = *(const float4*)&bta[t*4];
    float o0 = d0 * rstd * gv.x + bv.x;
    float o1 = d1 * rstd * gv.y + bv.y;
    float o2 = d2 * rstd * gv.z + bv.z;
    float o3 = d3 * rstd * gv.w + bv.w;
    u16x4 ob;
    ob[0] = f2bf(o0); ob[1] = f2bf(o1); ob[2] = f2bf(o2); ob[3] = f2bf(o3);
    *(u16x4*)&xbf[(size_t)row * D + t*4] = ob;
    if (WF32) {
        float4 of = {o0, o1, o2, o3};
        *(float4*)&(xf32 + (size_t)row * D)[t*4] = of;
    }
}

// ---------------------------------------------------------------------------
// Head: logits + loss + acc, single block. x8 is the compact (8,D) final rows.
// ---------------------------------------------------------------------------
__global__ void head_kernel(const float* __restrict__ x8,
                            const float* __restrict__ pw,
                            const float* __restrict__ pb,
                            const int* __restrict__ tgt,
                            float* __restrict__ out) {
    __shared__ float lg[40];
    int t = threadIdx.x;
    int w = t >> 6, lane = t & 63;
    for (int p = w; p < B * NA; p += 4) {
        int b = p / NA, a = p % NA;
        const float* xr = x8 + (size_t)b * D;
        const float* wr = pw + (size_t)a * D;
        float s = 0.f;
        for (int k = lane; k < D; k += 64) s += xr[k] * wr[k];
        #pragma unroll
        for (int msk = 1; msk < 64; msk <<= 1) s += __shfl_xor(s, msk);
        if (lane == 0) lg[p] = s + pb[a];
    }
    __syncthreads();
    if (t == 0) {
        float loss = 0.f, acc = 0.f;
        for (int b = 0; b < B; ++b) {
            const float* l = lg + b * NA;
            float mx = l[0]; int am = 0;
            for (int a = 1; a < NA; ++a) if (l[a] > mx) { mx = l[a]; am = a; }
            float se = 0.f;
            for (int a = 0; a < NA; ++a) se += expf(l[a] - mx);
            float lse = mx + logf(se);
            float mean_lp = 0.f;
            for (int a = 0; a < NA; ++a) mean_lp += (l[a] - lse);
            mean_lp *= (1.0f / NA);
            int tb = tgt[b];
            float nll = -(l[tb] - lse);
            loss += 0.9f * nll - 0.1f * mean_lp;
            acc += (am == tb) ? 1.f : 0.f;
        }
        out[0] = loss * (1.0f / B);
        out[1] = acc * (1.0f / B);
    }
}

// ---------------------------------------------------------------------------
extern "C" void kernel_launch(void* const* d_in, const int* in_sizes, int n_in,
                              void* d_out, int out_size, void* d_ws, size_t ws_size,
                              hipStream_t stream) {
    const float* states      = (const float*)d_in[0];
    const float* actions     = (const float*)d_in[1];
    const float* next_states = (const float*)d_in[2];
    const float* rewards     = (const float*)d_in[3];
    const float* pos         = (const float*)d_in[4];
    const float* ecw         = (const float*)d_in[5];
    const float* ecb         = (const float*)d_in[6];
    const float* table       = (const float*)d_in[7];
    const float* in_proj_w   = (const float*)d_in[8];
    const float* in_proj_b   = (const float*)d_in[9];
    const float* out_proj_w  = (const float*)d_in[10];
    const float* out_proj_b  = (const float*)d_in[11];
    const float* linear1_w   = (const float*)d_in[12];
    const float* linear1_b   = (const float*)d_in[13];
    const float* linear2_w   = (const float*)d_in[14];
    const float* linear2_b   = (const float*)d_in[15];
    const float* norm1_g     = (const float*)d_in[16];
    const float* norm1_b     = (const float*)d_in[17];
    const float* norm2_g     = (const float*)d_in[18];
    const float* norm2_b     = (const float*)d_in[19];
    const float* pred_w      = (const float*)d_in[20];
    const float* pred_b      = (const float*)d_in[21];
    const int*   query_states   = (const int*)d_in[22];
    const int*   target_actions = (const int*)d_in[23];

    float* out = (float*)d_out;

    // ---- workspace layout (byte offsets) ----
    char* W = (char*)d_ws;
    u16*   x_bf   = (u16*)  (W + 0);                 //  8 MB (bf16 residual)
    u16*   win_bf = (u16*)  (W + 8388608);           //  6 MB  } contiguous
    u16*   wout_bf= (u16*)  (W + 14680064);          //  2 MB  } weight
    u16*   wl1_bf = (u16*)  (W + 16777216);          //  8 MB  } region
    u16*   wl2_bf = (u16*)  (W + 25165824);          //  8 MB  }
    u16*   qkv_bf = (u16*)  (W + 33554432);          // 24 MB
    u16*   Vt     = (u16*)  (W + 58720256);          //  8 MB
    u16*   ff_bf  = (u16*)  (W + 33554432);          // 32 MB (aliases qkv+Vt)
    u16*   ctx_bf = (u16*)  (W + 100663296);         //  8 MB
    u16*   ybf    = (u16*)  (W + 109051904);         //  8 MB (bf16 GEMM y)
    float* fbuf   = (float*)(W + 117440512);         //  8 MB scratch

    // tail scratch lives inside fbuf
    float* x8     = fbuf;                    // 8x1024 f32
    float* xf8    = fbuf + 8192;             // 8x1024 f32
    u16*   y8     = (u16*)(fbuf + 16384);    // 8x1024 bf16
    u16*   x8_bf  = (u16*)(fbuf + 20480);    // 8x1024 bf16
    u16*   ff8_bf = (u16*)(fbuf + 24576);    // 8x4096 bf16
    u16*   y8b    = (u16*)(fbuf + 40960);    // 8x1024 bf16
    u16*   xf8_bf = (u16*)(fbuf + 45056);    // 8x1024 bf16 (sink)

    embed_kernel<<<(ML * D) / 256, 256, 0, stream>>>(
        states, actions, next_states, rewards, pos, ecw, ecb, table,
        query_states, x_bf);

    cvt_all_kernel<<<3145728 / 256, 256, 0, stream>>>(
        in_proj_w, out_proj_w, linear1_w, linear2_w, win_bf);

    const long LL = (long)L * L;
    for (int l = 0; l < NLAYERS; ++l) {
        float* attnL = out + 2 + (size_t)l * B * H * LL;

        // qkv -> bf16 (4096,3072); V also written transposed into Vt
        gemm128<1><<<dim3(3072/128, ML/128), 256, 0, stream>>>(
            x_bf, D, win_bf, D, qkv_bf, 3*D, in_proj_b, D, Vt);

        // fused scores + softmax + d_out P write + PV
        fused_attn<<<dim3(L/32, B*H), 256, 0, stream>>>(qkv_bf, Vt, attnL, ctx_bf);

        if (l < NLAYERS - 1) {
            // out_proj -> bf16   [64x128 tiles: 512 blocks = 2/CU]
            gemm64<<<dim3(D/128, ML/64), 256, 0, stream>>>(
                ctx_bf, D, wout_bf, D, ybf, D, out_proj_b, D);

            // x = LN(x + y)  (in place on bf16 stream)
            ln_add_kernel<0,0><<<ML, 256, 0, stream>>>(
                x_bf, ybf, x_bf, nullptr, norm1_g, norm1_b);

            // ff1 + gelu -> bf16 (4096,4096)
            gemm128<2><<<dim3(DFF/128, ML/128), 256, 0, stream>>>(
                x_bf, D, wl1_bf, D, ff_bf, DFF, linear1_b, D, nullptr);

            // ff2 -> bf16   [64x128 tiles: 512 blocks = 2/CU]
            gemm64<<<dim3(D/128, ML/64), 256, 0, stream>>>(
                ff_bf, DFF, wl2_bf, DFF, ybf, D, linear2_b, DFF);

            ln_add_kernel<0,0><<<ML, 256, 0, stream>>>(
                x_bf, ybf, x_bf, nullptr, norm2_g, norm2_b);
        } else {
            // ---- layer-4 tail: only token 511 of each batch feeds the head ----
            tail_gemv<0><<<dim3(D/256, B), 256, 0, stream>>>(
                ctx_bf + (size_t)(L-1) * D, (long)L * D, wout_bf, out_proj_b,
                y8, D, D);
            ln_add_kernel<1,1><<<B, 256, 0, stream>>>(
                x_bf, y8, x8_bf, x8, norm1_g, norm1_b);
            tail_gemv<2><<<dim3(DFF/256, B), 256, 0, stream>>>(
                x8_bf, (long)D, wl1_bf, linear1_b, ff8_bf, DFF, D);
            tail_gemv<0><<<dim3(D/256, B), 256, 0, stream>>>(
                ff8_bf, (long)DFF, wl2_bf, linear2_b, y8b, D, DFF);
            ln_add_kernel<0,1><<<B, 256, 0, stream>>>(
                x8_bf, y8b, xf8_bf, xf8, norm2_g, norm2_b);
        }
    }

    head_kernel<<<1, 256, 0, stream>>>(xf8, pred_w, pred_b, target_actions, out);
}